// Round 15
// baseline (411.568 us; speedup 1.0000x reference)
//
#include <hip/hip_runtime.h>
#include <hip/hip_bf16.h>

// Model dims
#define NN 2048
#define DS 64
#define DI 256
#define DV 64
#define KK 512
#define HH 4
#define HD 16
#define BB 2
#define TT 4
#define DCAT 192

typedef unsigned long long ull;

__device__ __forceinline__ float wave_sum(float v) {
#pragma unroll
    for (int o = 32; o > 0; o >>= 1) v += __shfl_xor(v, o);
    return v;
}
__device__ __forceinline__ float wave_max(float v) {
#pragma unroll
    for (int o = 32; o > 0; o >>= 1) v = fmaxf(v, __shfl_xor(v, o));
    return v;
}
__device__ __forceinline__ unsigned enc_f(float f) {
    unsigned u = __float_as_uint(f);
    return (u & 0x80000000u) ? ~u : (u | 0x80000000u);
}

// ---------------------------------------------------------------- K0: precompute
// blocks 0..7: xproj.  8..9: t=0 top-k identity.
// 10..57: Wqkv = attn_in_w @ W_vote.  58..73: Wsc.  74..89: Wsh.
__global__ __launch_bounds__(256) void k_pre(
    const float* __restrict__ x, const float* __restrict__ W_in,
    const float* __restrict__ attn_in_w, const float* __restrict__ W_vote,
    const float* __restrict__ attn_out_w, const float* __restrict__ Wfs,
    const float* __restrict__ Wfsh,
    float* __restrict__ xproj, int* __restrict__ col2slot, int* __restrict__ act_idx,
    float* __restrict__ Wqkv, float* __restrict__ Wsc, float* __restrict__ Wsh)
{
    int blk = blockIdx.x, tid = threadIdx.x;
    int w = tid >> 6, lane = tid & 63;
    if (blk < 8) {
        int b = blk >> 2, t = blk & 3;
        int r = tid >> 2, q = tid & 3;
        const float* xp = x + (b * TT + t) * DI + q * 64;
        const float* wr = W_in + r * DI + q * 64;
        float a = 0.f;
#pragma unroll
        for (int i = 0; i < 64; i++) a += xp[i] * wr[i];
        a += __shfl_xor(a, 1); a += __shfl_xor(a, 2);
        if (q == 0) xproj[(b * TT + t) * DS + r] = a;
    } else if (blk < 10) {
        int b = blk - 8;
        for (int i = tid; i < NN; i += 256) col2slot[b * NN + i] = (i < KK) ? i : -1;
        for (int i = tid; i < KK; i += 256) act_idx[b * KK + i] = i;
    } else if (blk < 58) {
        int r = (blk - 10) * 4 + w;                       // 0..191
        const float* ar = attn_in_w + r * 64;             // uniform -> s_load
        float acc = 0.f;
#pragma unroll
        for (int e = 0; e < 64; e++) acc += ar[e] * W_vote[e * 64 + lane];  // coalesced
        Wqkv[r * 64 + lane] = acc;
    } else if (blk < 74) {
        int r = (blk - 58) * 4 + w;                       // 0..63
        const float* ar = Wfs + r * 64;
        float acc = 0.f;
#pragma unroll
        for (int e = 0; e < 64; e++) acc += ar[e] * attn_out_w[e * 64 + lane];
        Wsc[r * 64 + lane] = acc;
    } else {
        int r = (blk - 74) * 4 + w;                       // 0..63
        const float* ar = Wfsh + r * 64;
        float acc = 0.f;
#pragma unroll
        for (int e = 0; e < 64; e++) acc += ar[e] * attn_out_w[e * 64 + lane];
        Wsh[r * 64 + lane] = acc;
    }
}

// ---------------------------------------------------------------- K1: core_a2
// 256 blocks (cg,og): rmsnorm -> z -> g -> u (16 rows) -> h_hat partial (64x64)
// written transposed to part16[gcol][og*64+o].
__global__ __launch_bounds__(256) void k_core_a(
    const float* __restrict__ h, const float* __restrict__ xproj,
    const int* __restrict__ act_idx, const float* __restrict__ norm_w,
    const float* __restrict__ Wg, const float* __restrict__ Wout,
    float* __restrict__ part16, int t)
{
    __shared__ char sm[34048];
    int tid = threadIdx.x;
    int cg = blockIdx.x >> 4;             // 0..15
    int og = blockIdx.x & 15;             // 0..15
    int c = tid & 63;
    int seg = __builtin_amdgcn_readfirstlane(tid >> 6);
    int b = cg >> 3;
    int sbase = (cg & 7) * 64;
    float* zt  = (float*)sm;              // 32768
    float* ssq = (float*)(sm + 32768);    // 1024
    float* rsb = (float*)(sm + 33792);    // 256
    {
        int n = act_idx[b * KK + sbase + c];
        float vals[32];
        float sq = 0.f;
        if (seg < 2) {
            const float* hp = h + ((size_t)(b * NN + n)) * DS + seg * 32;
#pragma unroll
            for (int i = 0; i < 32; i++) { float v = hp[i]; vals[i] = v; sq += v * v; }
        } else {
            const float* xp = xproj + (b * TT + t) * DS + (seg - 2) * 32;
#pragma unroll
            for (int i = 0; i < 32; i++) { float v = xp[i]; vals[i] = v; sq += v * v; }
        }
        ssq[seg * 64 + c] = sq;
        __syncthreads();
        if (tid < 64) {
            float s = ssq[tid] + ssq[64 + tid] + ssq[128 + tid] + ssq[192 + tid];
            rsb[tid] = rsqrtf(s * (1.0f / DCAT) + 1e-6f);
        }
        __syncthreads();
        {
            float rs = rsb[c];
#pragma unroll
            for (int i = 0; i < 32; i++) {
                int d = seg * 32 + i;
                zt[d * 64 + c] = norm_w[d] * vals[i] * rs;
            }
        }
    }
    __syncthreads();
    float z[128];
#pragma unroll
    for (int d = 0; d < 128; d++) z[d] = zt[d * 64 + c];
    __syncthreads();                      // zt region free after this
    float* u16  = (float*)sm;             // [16][64] 4096
    float* tile = (float*)(sm + 4096);    // [64][65] 16640
    int rbase = og * 16 + seg * 4;
    float ga[4];
#pragma unroll
    for (int r = 0; r < 4; r++) {
        const float* wr = Wg + (rbase + r) * DCAT;        // uniform -> s_load
        float acc = 0.f;
#pragma unroll
        for (int d = 0; d < 128; d++) acc += z[d] * wr[d];
        ga[r] = acc;
    }
#pragma unroll
    for (int r = 0; r < 4; r++) {
        const float* wr = Wg + (256 + rbase + r) * DCAT;
        float bacc = 0.f;
#pragma unroll
        for (int d = 0; d < 128; d++) bacc += z[d] * wr[d];
        float uu = ga[r] * (bacc / (1.f + expf(-bacc)));  // a * silu(b)
        u16[(seg * 4 + r) * 64 + c] = uu;
    }
    __syncthreads();
    // h_hat partial: out rows o (64), K-rows = og's 16 u-rows
    {
        int w = tid >> 6;
#pragma unroll
        for (int oi = 0; oi < 16; oi++) {
            int o = w * 16 + oi;
            const float* wr = Wout + o * 256 + og * 16;   // uniform -> s_load
            float acc = 0.f;
#pragma unroll
            for (int r = 0; r < 16; r++) acc += u16[r * 64 + c] * wr[r];
            tile[o * 65 + c] = acc;
        }
    }
    __syncthreads();
    {
        int gcolbase = cg * 64;
#pragma unroll
        for (int k = 0; k < 16; k++) {
            int flat = k * 256 + tid;
            int gl = flat >> 6, oo = flat & 63;
            part16[(size_t)(gcolbase + gl) * 1024 + og * 64 + oo] = tile[oo * 65 + gl];  // coalesced
        }
    }
}

// ---------------------------------------------------------------- K2: vqkv2
// 32 blocks: reduce 16 partials + h update, then qkv = Wqkv @ h_new directly.
__global__ __launch_bounds__(256) void k_vqkv(
    float* __restrict__ h, const float* __restrict__ part16,
    const int* __restrict__ act_idx, const float* __restrict__ Wqkv,
    float* __restrict__ qh, float* __restrict__ kh, float* __restrict__ vh)
{
    __shared__ float hn[64 * 33];         // [o][slot] pad-33
    __shared__ int an[32];
    int blk = blockIdx.x;
    int b = blk >> 4;
    int sbase = (blk & 15) * 32;
    int tid = threadIdx.x;
    int w = __builtin_amdgcn_readfirstlane(tid >> 6);
    int l = tid & 63;
    int c = l & 31, sub = l >> 5;
    if (tid < 32) an[tid] = act_idx[b * KK + sbase + tid];
    __syncthreads();
    // phase A: reduce 16 partials + h update (lane -> o, coalesced)
    {
        int o = tid & 63;
#pragma unroll
        for (int k = 0; k < 8; k++) {
            int s = (tid >> 6) + k * 4;                   // wave-uniform slot
            const float* pp = part16 + (size_t)(b * KK + sbase + s) * 1024 + o;
            float sum = 0.f;
#pragma unroll
            for (int kk = 0; kk < 16; kk++) sum += pp[kk * 64];
            size_t hidx = ((size_t)(b * NN + an[s])) * DS + o;
            float nh = h[hidx] + sum;
            h[hidx] = nh;
            hn[o * 33 + s] = nh;
        }
    }
    __syncthreads();
    // phase B: qkv = Wqkv @ h_new ; outputs [bh][hd][slot] coalesced
    float hh[32];
#pragma unroll
    for (int i = 0; i < 32; i++) hh[i] = hn[(sub * 32 + i) * 33 + c];
    int slot = sbase + c;
#pragma unroll 4
    for (int oi = 0; oi < 48; oi++) {
        int r = w * 48 + oi;
        const float* wr = Wqkv + r * 64 + sub * 32;       // uniform
        float a = 0.f;
#pragma unroll
        for (int i = 0; i < 32; i++) a += hh[i] * wr[i];
        a += __shfl_xor(a, 32);
        if (sub == 0) {
            if (r < 64) {
                qh[((b * HH + (r >> 4)) * HD + (r & 15)) * KK + slot] = a;
            } else if (r < 128) {
                int rr = r - 64;
                kh[((b * HH + (rr >> 4)) * HD + (rr & 15)) * KK + slot] = a;
            } else {
                int rr = r - 128;
                vh[((b * HH + (rr >> 4)) * HD + (rr & 15)) * KK + slot] = a;
            }
        }
    }
}

// ---------------------------------------------------------------- K3: mean-FiLM (blocks 0-1) + attention (blocks 2..1025)
__global__ __launch_bounds__(256) void k_attn(
    const float* __restrict__ qh, const float* __restrict__ kh,
    const float* __restrict__ vh, float* __restrict__ m_raw,
    const float* __restrict__ Wsc, const float* __restrict__ Wsh,
    float* __restrict__ fsm, float* __restrict__ fshm)
{
    __shared__ float partm[4 * 64];
    __shared__ float mr[64];
    int blk = blockIdx.x;
    int tid = threadIdx.x;
    if (blk < 2) {
        int b = blk;
        int w = tid >> 6, lane = tid & 63;
        float macc[64];
#pragma unroll
        for (int d = 0; d < 64; d++) macc[d] = 0.f;
        for (int s = tid; s < KK; s += 256) {
#pragma unroll
            for (int d = 0; d < 64; d++) macc[d] += vh[(b * DV + d) * KK + s];
        }
#pragma unroll
        for (int d = 0; d < 64; d++) macc[d] = wave_sum(macc[d]);
        if (lane == 0) {
#pragma unroll
            for (int d = 0; d < 64; d++) partm[w * 64 + d] = macc[d];
        }
        __syncthreads();
        if (tid < 64)
            mr[tid] = (partm[tid] + partm[64 + tid] + partm[128 + tid] + partm[192 + tid]) * (1.0f / KK);
        __syncthreads();
        if (tid < 64) {
            const float* ws_ = Wsc + tid * DV;
            const float* wh_ = Wsh + tid * DV;
            float sc = 0.f, sh = 0.f;
#pragma unroll
            for (int e = 0; e < 64; e++) { float zz = mr[e]; sc += ws_[e] * zz; sh += wh_[e] * zz; }
            fsm[b * DS + tid] = tanhf(sc);
            fshm[b * DS + tid] = sh;
        }
        return;
    }
    int wave = tid >> 6, lane = tid & 63;
    int task = (blk - 2) * 4 + wave;
    int qs = task & (KK - 1);
    int bh = task >> 9;
    float q[HD];
#pragma unroll
    for (int d = 0; d < HD; d++) q[d] = qh[(bh * HD + d) * KK + qs];
    const float* kp = kh + bh * HD * KK;
    const float* vp = vh + bh * HD * KK;
    float lg[8]; float mx = -1e30f;
#pragma unroll
    for (int i = 0; i < 8; i++) {
        int slot = i * 64 + lane;
        float a = 0.f;
#pragma unroll
        for (int d = 0; d < HD; d++) a += q[d] * kp[d * KK + slot];
        lg[i] = a * 0.25f;
        mx = fmaxf(mx, lg[i]);
    }
    mx = wave_max(mx);
    float p[8]; float sum = 0.f;
#pragma unroll
    for (int i = 0; i < 8; i++) { p[i] = __expf(lg[i] - mx); sum += p[i]; }
    sum = wave_sum(sum);
    float inv = 1.0f / sum;
    float acc[HD];
#pragma unroll
    for (int d = 0; d < HD; d++) acc[d] = 0.f;
#pragma unroll
    for (int i = 0; i < 8; i++) {
        int slot = i * 64 + lane;
        float pi = p[i];
#pragma unroll
        for (int d = 0; d < HD; d++) acc[d] += pi * vp[d * KK + slot];
    }
#pragma unroll
    for (int d = 0; d < HD; d++) acc[d] = wave_sum(acc[d]) * inv;
    if (lane == 0) {
        int b = bh >> 2, head = bh & 3;
#pragma unroll
        for (int d = 0; d < HD; d++)
            m_raw[(b * DV + head * HD + d) * KK + qs] = acc[d];
    }
}

// ---------------------------------------------------------------- K4: fused FiLM + gate + flash pool
//  + last-block-per-batch tail: out(t) + fast-radix top-k(t+1).
//    (once-per-block ACQ_REL done counter — proven R8-R10 pattern, no spins)
__global__ __launch_bounds__(256) void k_pool3(
    float* __restrict__ h, int* __restrict__ col2slot,
    const float* __restrict__ fsm, const float* __restrict__ fshm,
    const float* __restrict__ m_raw, const float* __restrict__ Wsc,
    const float* __restrict__ Wsh, const float* __restrict__ query,
    const float* __restrict__ W_gate, float* __restrict__ gate,
    float* __restrict__ ppool, float* __restrict__ psum, float* __restrict__ pmax,
    unsigned* __restrict__ done, const float* __restrict__ onw,
    const float* __restrict__ W_out, float* __restrict__ out,
    int* __restrict__ act_idx, int t)
{
    __shared__ char smem[26368];
    __shared__ float wms[4], wss[4];
    __shared__ int lastsh;
    __shared__ ull s_prefix; __shared__ int s_need; __shared__ unsigned ccnt;
    int* slots  = (int*)smem;               // 128
    float* M    = (float*)(smem + 128);     // [e][c] 8448
    float* SCT  = (float*)(smem + 8576);    // [c][o] 8320
    float* SHT  = (float*)(smem + 16896);   // 8320 -> 25216
    float* wvecs= (float*)(smem + 25216);   // 1024 -> 26240
    int blk = blockIdx.x;
    int b = blk >> 6;
    int base = (blk & 63) * 32;
    int tid = threadIdx.x;
    int w = tid >> 6, lane = tid & 63;
    if (tid < 32) slots[tid] = col2slot[b * NN + base + tid];
    __syncthreads();
    // gather messages per column (0 for inactive)
    for (int idx = tid; idx < 2048; idx += 256) {
        int d = idx >> 5, c = idx & 31;
        int s = slots[c];
        M[d * 33 + c] = (s >= 0) ? m_raw[(b * DV + d) * KK + s] : 0.f;
    }
    __syncthreads();
    // GEMV: SCT/SHT (active) else fsm/fshm
    {
        int sc_col = lane & 31, half = lane >> 5;
        int act = slots[sc_col] >= 0;
#pragma unroll 4
        for (int oi = 0; oi < 16; oi++) {
            int o = w * 16 + oi;
            const float* ws_ = Wsc + o * DV + half * 32;  // uniform -> s_load
            const float* wh_ = Wsh + o * DV + half * 32;
            float sc = 0.f, sh = 0.f;
#pragma unroll
            for (int e = 0; e < 32; e++) {
                float zz = M[(half * 32 + e) * 33 + sc_col];
                sc += ws_[e] * zz; sh += wh_[e] * zz;
            }
            sc += __shfl_xor(sc, 32); sh += __shfl_xor(sh, 32);
            if (half == 0) {
                SCT[sc_col * 65 + o] = act ? tanhf(sc) : fsm[b * DS + o];
                SHT[sc_col * 65 + o] = act ? sh : fshm[b * DS + o];
            }
        }
    }
    __syncthreads();
    // FiLM all columns + gate + flash pooling (single h pass)
    {
        float qv = query[lane] * 0.125f, wg = W_gate[lane];
        float wm = -1e30f, sw = 0.f, vec = 0.f;
#pragma unroll
        for (int ci = 0; ci < 8; ci++) {
            int cl = w * 8 + ci;
            int n = base + cl;
            size_t idx = ((size_t)(b * NN + n)) * DS + lane;
            float hv = h[idx];
            hv = hv * (1.f + SCT[cl * 65 + lane]) + SHT[cl * 65 + lane];
            h[idx] = hv;
            float lg = wave_sum(qv * hv);
            float gt = wave_sum(wg * hv);
            if (lane == 0) gate[b * NN + n] = gt;
            float nm = fmaxf(wm, lg);
            float scale = __expf(wm - nm);
            float e = __expf(lg - nm);
            sw = sw * scale + e;
            vec = vec * scale + e * hv;
            wm = nm;
        }
        wvecs[w * 64 + lane] = vec;
        if (lane == 0) { wms[w] = wm; wss[w] = sw; }
    }
    __syncthreads();
    if (tid < 64) {
        float m4 = fmaxf(fmaxf(wms[0], wms[1]), fmaxf(wms[2], wms[3]));
        float s = 0.f, v = 0.f;
#pragma unroll
        for (int ww = 0; ww < 4; ww++) {
            float e = __expf(wms[ww] - m4);
            s += wss[ww] * e;
            v += wvecs[ww * 64 + tid] * e;
        }
        ppool[blk * 64 + tid] = v;
        if (tid == 0) { psum[blk] = s; pmax[blk] = m4; }
    }
    // ---------------- last-block-per-batch tail: out(t) + topk(t+1)
    __syncthreads();
    if (tid == 0) {
        unsigned old = __hip_atomic_fetch_add(&done[t * BB + b], 1u,
                                              __ATOMIC_ACQ_REL, __HIP_MEMORY_SCOPE_AGENT);
        lastsh = (old == 63);
    }
    __syncthreads();
    if (!lastsh) return;
    // out(t): merge flash-pool partials + rmsnorm + W_out
    float* pn = (float*)(smem + 20480);   // 256B, clear of keys/hist regions
    if (tid < 64) {
        int d = tid;
        float gm = -1e30f;
        for (int i = 0; i < 64; i++) gm = fmaxf(gm, pmax[b * 64 + i]);
        float s = 0.f, v = 0.f;
        for (int i = 0; i < 64; i++) {
            float e = __expf(pmax[b * 64 + i] - gm);
            s += psum[b * 64 + i] * e;
            v += ppool[(b * 64 + i) * 64 + d] * e;
        }
        float val = v / s;
        float ss = wave_sum(val * val);
        float rs = rsqrtf(ss * (1.0f / DS) + 1e-6f);
        pn[d] = onw[d] * val * rs;
    }
    __syncthreads();
    {
        int o = tid;
        const float* wr = W_out + o * DS;
        float a = 0.f;
#pragma unroll
        for (int d = 0; d < DS; d++) a += pn[d] * wr[d];
        out[(b * TT + t) * DI + o] = a;
    }
    if (t == TT - 1) return;
    // fast-radix top-k(t+1) on gate[b] (wave-scan suffix sums)
    ull* keys = (ull*)smem;                              // 16384
    unsigned (*hist4)[256] = (unsigned(*)[256])(smem + 16384);  // 4096
    __syncthreads();                                     // pn no longer needed? (pn at 20480, keys 0..16384 — disjoint; sync for reuse of smem[0..] after SCT/SHT dead)
    if (tid == 0) ccnt = 0;
    for (int i = tid; i < NN; i += 256) {
        keys[i] = ((ull)enc_f(gate[b * NN + i]) << 11) | (unsigned)(NN - 1 - i);
        col2slot[b * NN + i] = -1;
    }
    ull prefix = 0, pmask = 0;
    int need = KK;
    for (int shift = 40; shift >= 0; shift -= 8) {
        for (int k = lane; k < 256; k += 64) hist4[w][k] = 0;
        __syncthreads();
        for (int i = tid; i < NN; i += 256) {
            ull k = keys[i];
            if ((k & pmask) == prefix)
                atomicAdd(&hist4[w][(unsigned)((k >> shift) & 255)], 1u);
        }
        __syncthreads();
        if (w == 0) {
            unsigned c0 = hist4[0][4 * lane]     + hist4[1][4 * lane]     + hist4[2][4 * lane]     + hist4[3][4 * lane];
            unsigned c1 = hist4[0][4 * lane + 1] + hist4[1][4 * lane + 1] + hist4[2][4 * lane + 1] + hist4[3][4 * lane + 1];
            unsigned c2 = hist4[0][4 * lane + 2] + hist4[1][4 * lane + 2] + hist4[2][4 * lane + 2] + hist4[3][4 * lane + 2];
            unsigned c3 = hist4[0][4 * lane + 3] + hist4[1][4 * lane + 3] + hist4[2][4 * lane + 3] + hist4[3][4 * lane + 3];
            unsigned s3 = c3, s2 = c2 + s3, s1 = c1 + s2, s0 = c0 + s1;
            unsigned run = s0;
#pragma unroll
            for (int off = 1; off < 64; off <<= 1) {
                unsigned v = __shfl_down(run, off);
                if (lane + off < 64) run += v;
            }
            unsigned higher = run - s0;
            unsigned suf0 = s0 + higher, suf1 = s1 + higher, suf2 = s2 + higher, suf3 = s3 + higher;
            unsigned nd = (unsigned)need;
            if (suf0 >= nd && suf1 < nd) { s_prefix = prefix | ((ull)(4 * lane)     << shift); s_need = need - (int)suf1; }
            if (suf1 >= nd && suf2 < nd) { s_prefix = prefix | ((ull)(4 * lane + 1) << shift); s_need = need - (int)suf2; }
            if (suf2 >= nd && suf3 < nd) { s_prefix = prefix | ((ull)(4 * lane + 2) << shift); s_need = need - (int)suf3; }
            if (suf3 >= nd && higher < nd) { s_prefix = prefix | ((ull)(4 * lane + 3) << shift); s_need = need - (int)higher; }
        }
        __syncthreads();
        prefix = s_prefix; need = s_need; pmask |= (0xFFull << shift);
    }
    for (int i = tid; i < NN; i += 256) {
        ull k = keys[i];
        if (k >= prefix) {
            unsigned p = atomicAdd(&ccnt, 1u);
            int n = NN - 1 - (int)(k & 2047ull);
            act_idx[b * KK + p] = n;
            col2slot[b * NN + n] = (int)p;
        }
    }
}

// ----------------------------------------------------------------
extern "C" void kernel_launch(void* const* d_in, const int* in_sizes, int n_in,
                              void* d_out, int out_size, void* d_ws, size_t ws_size,
                              hipStream_t stream)
{
    const float* x          = (const float*)d_in[0];
    const float* W_in       = (const float*)d_in[1];
    const float* core_norm_w= (const float*)d_in[2];
    const float* core_Wg    = (const float*)d_in[3];
    const float* core_Wout  = (const float*)d_in[4];
    const float* W_gate     = (const float*)d_in[5];
    const float* W_vote     = (const float*)d_in[6];
    const float* attn_in_w  = (const float*)d_in[7];
    const float* attn_out_w = (const float*)d_in[8];
    const float* Wfs        = (const float*)d_in[9];
    const float* Wfsh       = (const float*)d_in[10];
    const float* query      = (const float*)d_in[11];
    const float* onw        = (const float*)d_in[12];
    const float* W_out      = (const float*)d_in[13];
    float* out = (float*)d_out;

    float* ws = (float*)d_ws;
    float* h        = ws;                              // 262144 f
    unsigned* done  = (unsigned*)(h + (size_t)BB * NN * DS);  // 16 u32
    float* gate     = (float*)(done + 16);             // 4096 f
    float* xproj    = gate + BB * NN;                  // 512 f
    int*   col2slot = (int*)(xproj + BB * TT * DS);    // 4096
    int*   act_idx  = col2slot + BB * NN;              // 1024
    float* part16   = (float*)(act_idx + BB * KK);     // 1024*1024 f (4MB)
    float* qh       = part16 + 1024 * 1024;            // 65536 ([bh][hd][slot])
    float* kh       = qh + BB * HH * KK * HD;
    float* vh       = kh + BB * HH * KK * HD;
    float* m_raw    = vh + BB * HH * KK * HD;          // 65536 ([b][dv][slot])
    float* fsm      = m_raw + BB * DV * KK;            // 128
    float* fshm     = fsm + BB * DS;                   // 128
    float* ppool    = fshm + BB * DS;                  // 8192
    float* psum     = ppool + 128 * 64;                // 128
    float* pmax     = psum + 128;                      // 128
    float* Wqkv     = pmax + 128;                      // 12288
    float* Wsc      = Wqkv + 192 * 64;                 // 4096
    float* Wsh      = Wsc + 64 * 64;                   // 4096

    // zero h + done counters (contiguous)
    hipMemsetAsync(h, 0, (size_t)BB * NN * DS * sizeof(float) + 64, stream);

    k_pre<<<90, 256, 0, stream>>>(x, W_in, attn_in_w, W_vote, attn_out_w, Wfs, Wfsh,
                                  xproj, col2slot, act_idx, Wqkv, Wsc, Wsh);
    for (int t = 0; t < TT; t++) {
        k_core_a<<<256, 256, 0, stream>>>(h, xproj, act_idx, core_norm_w, core_Wg,
                                          core_Wout, part16, t);
        k_vqkv<<<32, 256, 0, stream>>>(h, part16, act_idx, Wqkv, qh, kh, vh);
        k_attn<<<1026, 256, 0, stream>>>(qh, kh, vh, m_raw, Wsc, Wsh, fsm, fshm);
        k_pool3<<<128, 256, 0, stream>>>(h, col2slot, fsm, fshm, m_raw, Wsc, Wsh,
                                         query, W_gate, gate, ppool, psum, pmax,
                                         done, onw, W_out, out, act_idx, t);
    }
}

// Round 16
// 353.556 us; speedup vs baseline: 1.1641x; 1.1641x over previous
//
#include <hip/hip_runtime.h>
#include <hip/hip_bf16.h>

// Model dims
#define NN 2048
#define DS 64
#define DI 256
#define DV 64
#define KK 512
#define HH 4
#define HD 16
#define BB 2
#define TT 4
#define DCAT 192

typedef unsigned long long ull;

__device__ __forceinline__ float wave_sum(float v) {
#pragma unroll
    for (int o = 32; o > 0; o >>= 1) v += __shfl_xor(v, o);
    return v;
}
__device__ __forceinline__ float wave_max(float v) {
#pragma unroll
    for (int o = 32; o > 0; o >>= 1) v = fmaxf(v, __shfl_xor(v, o));
    return v;
}
__device__ __forceinline__ unsigned enc_f(float f) {
    unsigned u = __float_as_uint(f);
    return (u & 0x80000000u) ? ~u : (u | 0x80000000u);
}

// ---------------------------------------------------------------- K0: precompute
// blocks 0..7: xproj.  8..9: t=0 top-k identity.
// 10..57: Wqkv = attn_in_w @ W_vote.  58..73: Wsc.  74..89: Wsh.
// 90..121: zero h (replaces the hipMemsetAsync dispatch).
__global__ __launch_bounds__(256) void k_pre(
    const float* __restrict__ x, const float* __restrict__ W_in,
    const float* __restrict__ attn_in_w, const float* __restrict__ W_vote,
    const float* __restrict__ attn_out_w, const float* __restrict__ Wfs,
    const float* __restrict__ Wfsh,
    float* __restrict__ xproj, int* __restrict__ col2slot, int* __restrict__ act_idx,
    float* __restrict__ Wqkv, float* __restrict__ Wsc, float* __restrict__ Wsh,
    float* __restrict__ h)
{
    int blk = blockIdx.x, tid = threadIdx.x;
    int w = tid >> 6, lane = tid & 63;
    if (blk < 8) {
        int b = blk >> 2, t = blk & 3;
        int r = tid >> 2, q = tid & 3;
        const float* xp = x + (b * TT + t) * DI + q * 64;
        const float* wr = W_in + r * DI + q * 64;
        float a = 0.f;
#pragma unroll
        for (int i = 0; i < 64; i++) a += xp[i] * wr[i];
        a += __shfl_xor(a, 1); a += __shfl_xor(a, 2);
        if (q == 0) xproj[(b * TT + t) * DS + r] = a;
    } else if (blk < 10) {
        int b = blk - 8;
        for (int i = tid; i < NN; i += 256) col2slot[b * NN + i] = (i < KK) ? i : -1;
        for (int i = tid; i < KK; i += 256) act_idx[b * KK + i] = i;
    } else if (blk < 58) {
        int r = (blk - 10) * 4 + w;                       // 0..191
        const float* ar = attn_in_w + r * 64;             // uniform -> s_load
        float acc = 0.f;
#pragma unroll
        for (int e = 0; e < 64; e++) acc += ar[e] * W_vote[e * 64 + lane];  // coalesced
        Wqkv[r * 64 + lane] = acc;
    } else if (blk < 74) {
        int r = (blk - 58) * 4 + w;                       // 0..63
        const float* ar = Wfs + r * 64;
        float acc = 0.f;
#pragma unroll
        for (int e = 0; e < 64; e++) acc += ar[e] * attn_out_w[e * 64 + lane];
        Wsc[r * 64 + lane] = acc;
    } else if (blk < 90) {
        int r = (blk - 74) * 4 + w;                       // 0..63
        const float* ar = Wfsh + r * 64;
        float acc = 0.f;
#pragma unroll
        for (int e = 0; e < 64; e++) acc += ar[e] * attn_out_w[e * 64 + lane];
        Wsh[r * 64 + lane] = acc;
    } else {
        // zero h: 262144 floats = 65536 float4; 32 blocks x 256 threads x 8
        float4 z4 = {0.f, 0.f, 0.f, 0.f};
        float4* h4 = (float4*)h;
        int base = (blk - 90) * 2048 + tid;
#pragma unroll
        for (int k = 0; k < 8; k++) h4[base + k * 256] = z4;
    }
}

// ---------------------------------------------------------------- K1: head
// blocks 0-1: fast-radix top-k(t) (t<TT). blocks 2-3: out(t-1) (t>0).
__global__ __launch_bounds__(256) void k_head(
    const float* __restrict__ gate, int* __restrict__ col2slot,
    int* __restrict__ act_idx,
    const float* __restrict__ ppool, const float* __restrict__ psum,
    const float* __restrict__ pmax, const float* __restrict__ onw,
    const float* __restrict__ W_out, float* __restrict__ out, int t)
{
    __shared__ char sm[20480];            // keys 16384 | hist4 4096
    __shared__ ull s_prefix; __shared__ int s_need; __shared__ unsigned ccnt;
    __shared__ float pn[64];
    int blk = blockIdx.x, tid = threadIdx.x;
    int w = tid >> 6, lane = tid & 63;
    if (blk < 2) {
        if (t >= TT) return;
        int b = blk;
        ull* keys = (ull*)sm;
        unsigned (*hist4)[256] = (unsigned(*)[256])(sm + 16384);
        if (tid == 0) ccnt = 0;
        for (int i = tid; i < NN; i += 256) {
            keys[i] = ((ull)enc_f(gate[b * NN + i]) << 11) | (unsigned)(NN - 1 - i);
            col2slot[b * NN + i] = -1;
        }
        ull prefix = 0, pmask = 0;
        int need = KK;
        for (int shift = 40; shift >= 0; shift -= 8) {
            for (int k = lane; k < 256; k += 64) hist4[w][k] = 0;
            __syncthreads();
            for (int i = tid; i < NN; i += 256) {
                ull k = keys[i];
                if ((k & pmask) == prefix)
                    atomicAdd(&hist4[w][(unsigned)((k >> shift) & 255)], 1u);
            }
            __syncthreads();
            if (w == 0) {
                unsigned c0 = hist4[0][4 * lane]     + hist4[1][4 * lane]     + hist4[2][4 * lane]     + hist4[3][4 * lane];
                unsigned c1 = hist4[0][4 * lane + 1] + hist4[1][4 * lane + 1] + hist4[2][4 * lane + 1] + hist4[3][4 * lane + 1];
                unsigned c2 = hist4[0][4 * lane + 2] + hist4[1][4 * lane + 2] + hist4[2][4 * lane + 2] + hist4[3][4 * lane + 2];
                unsigned c3 = hist4[0][4 * lane + 3] + hist4[1][4 * lane + 3] + hist4[2][4 * lane + 3] + hist4[3][4 * lane + 3];
                unsigned s3 = c3, s2 = c2 + s3, s1 = c1 + s2, s0 = c0 + s1;
                unsigned run = s0;
#pragma unroll
                for (int off = 1; off < 64; off <<= 1) {
                    unsigned v = __shfl_down(run, off);
                    if (lane + off < 64) run += v;
                }
                unsigned higher = run - s0;
                unsigned suf0 = s0 + higher, suf1 = s1 + higher, suf2 = s2 + higher, suf3 = s3 + higher;
                unsigned nd = (unsigned)need;
                if (suf0 >= nd && suf1 < nd) { s_prefix = prefix | ((ull)(4 * lane)     << shift); s_need = need - (int)suf1; }
                if (suf1 >= nd && suf2 < nd) { s_prefix = prefix | ((ull)(4 * lane + 1) << shift); s_need = need - (int)suf2; }
                if (suf2 >= nd && suf3 < nd) { s_prefix = prefix | ((ull)(4 * lane + 2) << shift); s_need = need - (int)suf3; }
                if (suf3 >= nd && higher < nd) { s_prefix = prefix | ((ull)(4 * lane + 3) << shift); s_need = need - (int)higher; }
            }
            __syncthreads();
            prefix = s_prefix; need = s_need; pmask |= (0xFFull << shift);
        }
        for (int i = tid; i < NN; i += 256) {
            ull k = keys[i];
            if (k >= prefix) {
                unsigned p = atomicAdd(&ccnt, 1u);
                int n = NN - 1 - (int)(k & 2047ull);
                act_idx[b * KK + p] = n;
                col2slot[b * NN + n] = (int)p;
            }
        }
    } else {
        if (t == 0) return;
        int b = blk - 2;
        if (tid < 64) {
            int d = tid;
            float gm = -1e30f;
            for (int i = 0; i < 64; i++) gm = fmaxf(gm, pmax[b * 64 + i]);
            float s = 0.f, v = 0.f;
            for (int i = 0; i < 64; i++) {
                float e = __expf(pmax[b * 64 + i] - gm);
                s += psum[b * 64 + i] * e;
                v += ppool[(b * 64 + i) * 64 + d] * e;
            }
            float val = v / s;
            float ss = wave_sum(val * val);
            float rs = rsqrtf(ss * (1.0f / DS) + 1e-6f);
            pn[d] = onw[d] * val * rs;
        }
        __syncthreads();
        {
            int o = tid;
            const float* wr = W_out + o * DS;
            float a = 0.f;
#pragma unroll
            for (int d = 0; d < DS; d++) a += pn[d] * wr[d];
            out[(b * TT + (t - 1)) * DI + o] = a;
        }
    }
}

// ---------------------------------------------------------------- K2: core_a2
// 256 blocks (cg,og): rmsnorm -> z -> g -> u (16 rows) -> h_hat partial (64x64)
// written transposed to part16[gcol][og*64+o].
__global__ __launch_bounds__(256) void k_core_a(
    const float* __restrict__ h, const float* __restrict__ xproj,
    const int* __restrict__ act_idx, const float* __restrict__ norm_w,
    const float* __restrict__ Wg, const float* __restrict__ Wout,
    float* __restrict__ part16, int t)
{
    __shared__ char sm[34048];
    int tid = threadIdx.x;
    int cg = blockIdx.x >> 4;             // 0..15
    int og = blockIdx.x & 15;             // 0..15
    int c = tid & 63;
    int seg = __builtin_amdgcn_readfirstlane(tid >> 6);
    int b = cg >> 3;
    int sbase = (cg & 7) * 64;
    float* zt  = (float*)sm;              // 32768
    float* ssq = (float*)(sm + 32768);    // 1024
    float* rsb = (float*)(sm + 33792);    // 256
    {
        int n = act_idx[b * KK + sbase + c];
        float vals[32];
        float sq = 0.f;
        if (seg < 2) {
            const float* hp = h + ((size_t)(b * NN + n)) * DS + seg * 32;
#pragma unroll
            for (int i = 0; i < 32; i++) { float v = hp[i]; vals[i] = v; sq += v * v; }
        } else {
            const float* xp = xproj + (b * TT + t) * DS + (seg - 2) * 32;
#pragma unroll
            for (int i = 0; i < 32; i++) { float v = xp[i]; vals[i] = v; sq += v * v; }
        }
        ssq[seg * 64 + c] = sq;
        __syncthreads();
        if (tid < 64) {
            float s = ssq[tid] + ssq[64 + tid] + ssq[128 + tid] + ssq[192 + tid];
            rsb[tid] = rsqrtf(s * (1.0f / DCAT) + 1e-6f);
        }
        __syncthreads();
        {
            float rs = rsb[c];
#pragma unroll
            for (int i = 0; i < 32; i++) {
                int d = seg * 32 + i;
                zt[d * 64 + c] = norm_w[d] * vals[i] * rs;
            }
        }
    }
    __syncthreads();
    float z[128];
#pragma unroll
    for (int d = 0; d < 128; d++) z[d] = zt[d * 64 + c];
    __syncthreads();                      // zt region free after this
    float* u16  = (float*)sm;             // [16][64] 4096
    float* tile = (float*)(sm + 4096);    // [64][65] 16640
    int rbase = og * 16 + seg * 4;
    float ga[4];
#pragma unroll
    for (int r = 0; r < 4; r++) {
        const float* wr = Wg + (rbase + r) * DCAT;        // uniform -> s_load
        float acc = 0.f;
#pragma unroll
        for (int d = 0; d < 128; d++) acc += z[d] * wr[d];
        ga[r] = acc;
    }
#pragma unroll
    for (int r = 0; r < 4; r++) {
        const float* wr = Wg + (256 + rbase + r) * DCAT;
        float bacc = 0.f;
#pragma unroll
        for (int d = 0; d < 128; d++) bacc += z[d] * wr[d];
        float uu = ga[r] * (bacc / (1.f + expf(-bacc)));  // a * silu(b)
        u16[(seg * 4 + r) * 64 + c] = uu;
    }
    __syncthreads();
    // h_hat partial: out rows o (64), K-rows = og's 16 u-rows
    {
        int w = tid >> 6;
#pragma unroll
        for (int oi = 0; oi < 16; oi++) {
            int o = w * 16 + oi;
            const float* wr = Wout + o * 256 + og * 16;   // uniform -> s_load
            float acc = 0.f;
#pragma unroll
            for (int r = 0; r < 16; r++) acc += u16[r * 64 + c] * wr[r];
            tile[o * 65 + c] = acc;
        }
    }
    __syncthreads();
    {
        int gcolbase = cg * 64;
#pragma unroll
        for (int k = 0; k < 16; k++) {
            int flat = k * 256 + tid;
            int gl = flat >> 6, oo = flat & 63;
            part16[(size_t)(gcolbase + gl) * 1024 + og * 64 + oo] = tile[oo * 65 + gl];  // coalesced
        }
    }
}

// ---------------------------------------------------------------- K3: vqkv2
// 32 blocks: reduce 16 partials + h update, then qkv = Wqkv @ h_new directly.
__global__ __launch_bounds__(256) void k_vqkv(
    float* __restrict__ h, const float* __restrict__ part16,
    const int* __restrict__ act_idx, const float* __restrict__ Wqkv,
    float* __restrict__ qh, float* __restrict__ kh, float* __restrict__ vh)
{
    __shared__ float hn[64 * 33];         // [o][slot] pad-33
    __shared__ int an[32];
    int blk = blockIdx.x;
    int b = blk >> 4;
    int sbase = (blk & 15) * 32;
    int tid = threadIdx.x;
    int w = __builtin_amdgcn_readfirstlane(tid >> 6);
    int l = tid & 63;
    int c = l & 31, sub = l >> 5;
    if (tid < 32) an[tid] = act_idx[b * KK + sbase + tid];
    __syncthreads();
    // phase A: reduce 16 partials + h update (lane -> o, coalesced)
    {
        int o = tid & 63;
#pragma unroll
        for (int k = 0; k < 8; k++) {
            int s = (tid >> 6) + k * 4;                   // wave-uniform slot
            const float* pp = part16 + (size_t)(b * KK + sbase + s) * 1024 + o;
            float sum = 0.f;
#pragma unroll
            for (int kk = 0; kk < 16; kk++) sum += pp[kk * 64];
            size_t hidx = ((size_t)(b * NN + an[s])) * DS + o;
            float nh = h[hidx] + sum;
            h[hidx] = nh;
            hn[o * 33 + s] = nh;
        }
    }
    __syncthreads();
    // phase B: qkv = Wqkv @ h_new ; outputs [bh][hd][slot] coalesced
    float hh[32];
#pragma unroll
    for (int i = 0; i < 32; i++) hh[i] = hn[(sub * 32 + i) * 33 + c];
    int slot = sbase + c;
#pragma unroll 4
    for (int oi = 0; oi < 48; oi++) {
        int r = w * 48 + oi;
        const float* wr = Wqkv + r * 64 + sub * 32;       // uniform
        float a = 0.f;
#pragma unroll
        for (int i = 0; i < 32; i++) a += hh[i] * wr[i];
        a += __shfl_xor(a, 32);
        if (sub == 0) {
            if (r < 64) {
                qh[((b * HH + (r >> 4)) * HD + (r & 15)) * KK + slot] = a;
            } else if (r < 128) {
                int rr = r - 64;
                kh[((b * HH + (rr >> 4)) * HD + (rr & 15)) * KK + slot] = a;
            } else {
                int rr = r - 128;
                vh[((b * HH + (rr >> 4)) * HD + (rr & 15)) * KK + slot] = a;
            }
        }
    }
}

// ---------------------------------------------------------------- K4: mean-FiLM (blocks 0-1) + attention (blocks 2..1025)
__global__ __launch_bounds__(256) void k_attn(
    const float* __restrict__ qh, const float* __restrict__ kh,
    const float* __restrict__ vh, float* __restrict__ m_raw,
    const float* __restrict__ Wsc, const float* __restrict__ Wsh,
    float* __restrict__ fsm, float* __restrict__ fshm)
{
    __shared__ float partm[4 * 64];
    __shared__ float mr[64];
    int blk = blockIdx.x;
    int tid = threadIdx.x;
    if (blk < 2) {
        int b = blk;
        int w = tid >> 6, lane = tid & 63;
        float macc[64];
#pragma unroll
        for (int d = 0; d < 64; d++) macc[d] = 0.f;
        for (int s = tid; s < KK; s += 256) {
#pragma unroll
            for (int d = 0; d < 64; d++) macc[d] += vh[(b * DV + d) * KK + s];
        }
#pragma unroll
        for (int d = 0; d < 64; d++) macc[d] = wave_sum(macc[d]);
        if (lane == 0) {
#pragma unroll
            for (int d = 0; d < 64; d++) partm[w * 64 + d] = macc[d];
        }
        __syncthreads();
        if (tid < 64)
            mr[tid] = (partm[tid] + partm[64 + tid] + partm[128 + tid] + partm[192 + tid]) * (1.0f / KK);
        __syncthreads();
        if (tid < 64) {
            const float* ws_ = Wsc + tid * DV;
            const float* wh_ = Wsh + tid * DV;
            float sc = 0.f, sh = 0.f;
#pragma unroll
            for (int e = 0; e < 64; e++) { float zz = mr[e]; sc += ws_[e] * zz; sh += wh_[e] * zz; }
            fsm[b * DS + tid] = tanhf(sc);
            fshm[b * DS + tid] = sh;
        }
        return;
    }
    int wave = tid >> 6, lane = tid & 63;
    int task = (blk - 2) * 4 + wave;
    int qs = task & (KK - 1);
    int bh = task >> 9;
    float q[HD];
#pragma unroll
    for (int d = 0; d < HD; d++) q[d] = qh[(bh * HD + d) * KK + qs];
    const float* kp = kh + bh * HD * KK;
    const float* vp = vh + bh * HD * KK;
    float lg[8]; float mx = -1e30f;
#pragma unroll
    for (int i = 0; i < 8; i++) {
        int slot = i * 64 + lane;
        float a = 0.f;
#pragma unroll
        for (int d = 0; d < HD; d++) a += q[d] * kp[d * KK + slot];
        lg[i] = a * 0.25f;
        mx = fmaxf(mx, lg[i]);
    }
    mx = wave_max(mx);
    float p[8]; float sum = 0.f;
#pragma unroll
    for (int i = 0; i < 8; i++) { p[i] = __expf(lg[i] - mx); sum += p[i]; }
    sum = wave_sum(sum);
    float inv = 1.0f / sum;
    float acc[HD];
#pragma unroll
    for (int d = 0; d < HD; d++) acc[d] = 0.f;
#pragma unroll
    for (int i = 0; i < 8; i++) {
        int slot = i * 64 + lane;
        float pi = p[i];
#pragma unroll
        for (int d = 0; d < HD; d++) acc[d] += pi * vp[d * KK + slot];
    }
#pragma unroll
    for (int d = 0; d < HD; d++) acc[d] = wave_sum(acc[d]) * inv;
    if (lane == 0) {
        int b = bh >> 2, head = bh & 3;
#pragma unroll
        for (int d = 0; d < HD; d++)
            m_raw[(b * DV + head * HD + d) * KK + qs] = acc[d];
    }
}

// ---------------------------------------------------------------- K5: fused FiLM(all columns) + gate + flash pool
// 128 blocks; block = 32 columns. Active: sct/sht via Wsc/Wsh GEMV on gathered
// m_raw; inactive: fsm/fshm. Then FiLM + gate + pooling in one h pass.
__global__ __launch_bounds__(256) void k_pool3(
    float* __restrict__ h, const int* __restrict__ col2slot,
    const float* __restrict__ fsm, const float* __restrict__ fshm,
    const float* __restrict__ m_raw, const float* __restrict__ Wsc,
    const float* __restrict__ Wsh, const float* __restrict__ query,
    const float* __restrict__ W_gate, float* __restrict__ gate,
    float* __restrict__ ppool, float* __restrict__ psum, float* __restrict__ pmax)
{
    __shared__ int slots[32];
    __shared__ float M[64 * 33];          // [e][c] 8448 B
    __shared__ float SCT[32 * 65];        // [c][o] 8320 B
    __shared__ float SHT[32 * 65];        // 8320 B
    __shared__ float wvecs[4][64];
    __shared__ float wms[4], wss[4];
    int blk = blockIdx.x;
    int b = blk >> 6;
    int base = (blk & 63) * 32;
    int tid = threadIdx.x;
    int w = tid >> 6, lane = tid & 63;
    if (tid < 32) slots[tid] = col2slot[b * NN + base + tid];
    __syncthreads();
    // gather messages per column (0 for inactive)
    for (int idx = tid; idx < 2048; idx += 256) {
        int d = idx >> 5, c = idx & 31;
        int s = slots[c];
        M[d * 33 + c] = (s >= 0) ? m_raw[(b * DV + d) * KK + s] : 0.f;
    }
    __syncthreads();
    // GEMV: SCT[c][o] = tanh(Wsc @ m_c), SHT[c][o] = Wsh @ m_c (active); fsm/fshm (inactive)
    {
        int sc_col = lane & 31, half = lane >> 5;
        int act = slots[sc_col] >= 0;
#pragma unroll 4
        for (int oi = 0; oi < 16; oi++) {
            int o = w * 16 + oi;
            const float* ws_ = Wsc + o * DV + half * 32;  // uniform -> s_load
            const float* wh_ = Wsh + o * DV + half * 32;
            float sc = 0.f, sh = 0.f;
#pragma unroll
            for (int e = 0; e < 32; e++) {
                float zz = M[(half * 32 + e) * 33 + sc_col];
                sc += ws_[e] * zz; sh += wh_[e] * zz;
            }
            sc += __shfl_xor(sc, 32); sh += __shfl_xor(sh, 32);
            if (half == 0) {
                SCT[sc_col * 65 + o] = act ? tanhf(sc) : fsm[b * DS + o];
                SHT[sc_col * 65 + o] = act ? sh : fshm[b * DS + o];
            }
        }
    }
    __syncthreads();
    // FiLM all columns + gate + flash pooling (single h pass)
    float qv = query[lane] * 0.125f, wg = W_gate[lane];
    float wm = -1e30f, sw = 0.f, vec = 0.f;
#pragma unroll
    for (int ci = 0; ci < 8; ci++) {
        int cl = w * 8 + ci;
        int n = base + cl;
        size_t idx = ((size_t)(b * NN + n)) * DS + lane;
        float hv = h[idx];
        hv = hv * (1.f + SCT[cl * 65 + lane]) + SHT[cl * 65 + lane];
        h[idx] = hv;
        float lg = wave_sum(qv * hv);
        float gt = wave_sum(wg * hv);
        if (lane == 0) gate[b * NN + n] = gt;
        float nm = fmaxf(wm, lg);
        float scale = __expf(wm - nm);
        float e = __expf(lg - nm);
        sw = sw * scale + e;
        vec = vec * scale + e * hv;
        wm = nm;
    }
    wvecs[w][lane] = vec;
    if (lane == 0) { wms[w] = wm; wss[w] = sw; }
    __syncthreads();
    if (tid < 64) {
        float m4 = fmaxf(fmaxf(wms[0], wms[1]), fmaxf(wms[2], wms[3]));
        float s = 0.f, v = 0.f;
#pragma unroll
        for (int ww = 0; ww < 4; ww++) {
            float e = __expf(wms[ww] - m4);
            s += wss[ww] * e;
            v += wvecs[ww][tid] * e;
        }
        ppool[blk * 64 + tid] = v;
        if (tid == 0) { psum[blk] = s; pmax[blk] = m4; }
    }
}

// ----------------------------------------------------------------
extern "C" void kernel_launch(void* const* d_in, const int* in_sizes, int n_in,
                              void* d_out, int out_size, void* d_ws, size_t ws_size,
                              hipStream_t stream)
{
    const float* x          = (const float*)d_in[0];
    const float* W_in       = (const float*)d_in[1];
    const float* core_norm_w= (const float*)d_in[2];
    const float* core_Wg    = (const float*)d_in[3];
    const float* core_Wout  = (const float*)d_in[4];
    const float* W_gate     = (const float*)d_in[5];
    const float* W_vote     = (const float*)d_in[6];
    const float* attn_in_w  = (const float*)d_in[7];
    const float* attn_out_w = (const float*)d_in[8];
    const float* Wfs        = (const float*)d_in[9];
    const float* Wfsh       = (const float*)d_in[10];
    const float* query      = (const float*)d_in[11];
    const float* onw        = (const float*)d_in[12];
    const float* W_out      = (const float*)d_in[13];
    float* out = (float*)d_out;

    float* ws = (float*)d_ws;
    float* h        = ws;                              // 262144 f
    float* gate     = h + (size_t)BB * NN * DS;        // 4096 f
    float* xproj    = gate + BB * NN;                  // 512 f
    int*   col2slot = (int*)(xproj + BB * TT * DS);    // 4096
    int*   act_idx  = col2slot + BB * NN;              // 1024
    float* part16   = (float*)(act_idx + BB * KK);     // 1024*1024 f (4MB)
    float* qh       = part16 + 1024 * 1024;            // 65536 ([bh][hd][slot])
    float* kh       = qh + BB * HH * KK * HD;
    float* vh       = kh + BB * HH * KK * HD;
    float* m_raw    = vh + BB * HH * KK * HD;          // 65536 ([b][dv][slot])
    float* fsm      = m_raw + BB * DV * KK;            // 128
    float* fshm     = fsm + BB * DS;                   // 128
    float* ppool    = fshm + BB * DS;                  // 8192
    float* psum     = ppool + 128 * 64;                // 128
    float* pmax     = psum + 128;                      // 128
    float* Wqkv     = pmax + 128;                      // 12288
    float* Wsc      = Wqkv + 192 * 64;                 // 4096
    float* Wsh      = Wsc + 64 * 64;                   // 4096

    k_pre<<<122, 256, 0, stream>>>(x, W_in, attn_in_w, W_vote, attn_out_w, Wfs, Wfsh,
                                   xproj, col2slot, act_idx, Wqkv, Wsc, Wsh, h);
    for (int t = 0; t < TT; t++) {
        if (t > 0)
            k_head<<<4, 256, 0, stream>>>(gate, col2slot, act_idx, ppool, psum, pmax,
                                          onw, W_out, out, t);
        k_core_a<<<256, 256, 0, stream>>>(h, xproj, act_idx, core_norm_w, core_Wg,
                                          core_Wout, part16, t);
        k_vqkv<<<32, 256, 0, stream>>>(h, part16, act_idx, Wqkv, qh, kh, vh);
        k_attn<<<1026, 256, 0, stream>>>(qh, kh, vh, m_raw, Wsc, Wsh, fsm, fshm);
        k_pool3<<<128, 256, 0, stream>>>(h, col2slot, fsm, fshm, m_raw, Wsc, Wsh,
                                         query, W_gate, gate, ppool, psum, pmax);
    }
    k_head<<<4, 256, 0, stream>>>(gate, col2slot, act_idx, ppool, psum, pmax,
                                  onw, W_out, out, TT);
}